// Round 17
// baseline (154.741 us; speedup 1.0000x reference)
//
#include <hip/hip_runtime.h>
#include <cstddef>
#include <cstdint>

#define TS 2048   // sequence length S
#define TD 512    // model dim D
#define TH 8      // heads
#define TDH 64    // head dim
#define CAP 256   // support entries per head list (ballot fallback beyond)
#define QCMAX 1024 // slab cap: 16*QCMAX*2048*2B = 67 MB -> L3-resident

typedef float f32x4 __attribute__((ext_vector_type(4)));
typedef short short8v __attribute__((ext_vector_type(8)));
typedef _Float16 half4v __attribute__((ext_vector_type(4)));
typedef _Float16 half8v __attribute__((ext_vector_type(8)));

__device__ __forceinline__ unsigned short f2bf(float f) {
  unsigned u = __builtin_bit_cast(unsigned, f);
  u += 0x7fff + ((u >> 16) & 1);          // RNE
  return (unsigned short)(u >> 16);
}

// ---------------------------------------------------------------------------
// cvt_all: one launch converts x, Wq, Wk, Wv, Wout -> bf16 buffers.
// ---------------------------------------------------------------------------
__global__ __launch_bounds__(256) void cvt_all(
    const float* __restrict__ x,  const float* __restrict__ Wq,
    const float* __restrict__ Wk, const float* __restrict__ Wv,
    const float* __restrict__ Wout,
    short* __restrict__ xb,  short* __restrict__ Wqb,
    short* __restrict__ Wkb, short* __restrict__ Wvb,
    short* __restrict__ Wob)
{
  const int b = blockIdx.x;
  const float* src; short* dst; int off;
  if (b < 1024)      { src = x;    dst = xb;  off = b; }
  else if (b < 1152) { src = Wq;   dst = Wqb; off = b - 1024; }
  else if (b < 1280) { src = Wk;   dst = Wkb; off = b - 1152; }
  else if (b < 1296) { src = Wv;   dst = Wvb; off = b - 1280; }
  else               { src = Wout; dst = Wob; off = b - 1296; }
  const int i = (off * 256 + threadIdx.x) << 3;
  float4 f0 = *(const float4*)(src + i);
  float4 f1 = *(const float4*)(src + i + 4);
  short8v v;
  v[0] = (short)f2bf(f0.x); v[1] = (short)f2bf(f0.y);
  v[2] = (short)f2bf(f0.z); v[3] = (short)f2bf(f0.w);
  v[4] = (short)f2bf(f1.x); v[5] = (short)f2bf(f1.y);
  v[6] = (short)f2bf(f1.z); v[7] = (short)f2bf(f1.w);
  *(short8v*)(dst + i) = v;
}

// ---------------------------------------------------------------------------
// Fused QKV projection (proven R9-R16).
// ---------------------------------------------------------------------------
__global__ __launch_bounds__(256) void proj_gemm(
    const short* __restrict__ xb,
    const short* __restrict__ Wqb, const float* __restrict__ bq,
    const short* __restrict__ Wkb, const float* __restrict__ bk,
    const short* __restrict__ Wvb, const float* __restrict__ bv,
    short* __restrict__ Qh, short* __restrict__ Kh, float* __restrict__ Vb)
{
  __shared__ short As[64][40];
  __shared__ short Bs[64][40];

  const int by = blockIdx.y;
  const short* W; const float* bias; int N; int col0; int outsel;
  if (by < 8)       { W = Wqb; bias = bq; N = TD;  col0 = by * 64;       outsel = 0; }
  else if (by < 16) { W = Wkb; bias = bk; N = TD;  col0 = (by - 8) * 64; outsel = 1; }
  else              { W = Wvb; bias = bv; N = TDH; col0 = 0;             outsel = 2; }

  const int tid  = threadIdx.x;
  const int w    = tid >> 6;
  const int lane = tid & 63;
  const int g    = lane >> 4;
  const int lc16 = lane & 15;
  const int wm   = w >> 1;
  const int wn   = w & 1;
  const int row0 = blockIdx.x * 64;

  const int ar = tid >> 2;
  const int ak = (tid & 3) << 3;
  const int wk = tid >> 3;
  const int wn8 = (tid & 7) << 3;

  f32x4 acc[2][2];
#pragma unroll
  for (int i = 0; i < 2; ++i)
#pragma unroll
    for (int j = 0; j < 2; ++j) acc[i][j] = (f32x4){0.f, 0.f, 0.f, 0.f};

  for (int kt = 0; kt < TD; kt += 32) {
    {
      short8v v = *(const short8v*)(xb + (size_t)(row0 + ar) * TD + kt + ak);
      *(short8v*)&As[ar][ak] = v;
    }
    {
      short8v v = *(const short8v*)(W + (size_t)(kt + wk) * N + col0 + wn8);
      Bs[wn8 + 0][wk] = v[0];
      Bs[wn8 + 1][wk] = v[1];
      Bs[wn8 + 2][wk] = v[2];
      Bs[wn8 + 3][wk] = v[3];
      Bs[wn8 + 4][wk] = v[4];
      Bs[wn8 + 5][wk] = v[5];
      Bs[wn8 + 6][wk] = v[6];
      Bs[wn8 + 7][wk] = v[7];
    }
    __syncthreads();

    short8v a0 = *(const short8v*)&As[wm * 32 + lc16][g * 8];
    short8v a1 = *(const short8v*)&As[wm * 32 + 16 + lc16][g * 8];
    short8v b0 = *(const short8v*)&Bs[wn * 32 + lc16][g * 8];
    short8v b1 = *(const short8v*)&Bs[wn * 32 + 16 + lc16][g * 8];
    acc[0][0] = __builtin_amdgcn_mfma_f32_16x16x32_bf16(a0, b0, acc[0][0], 0, 0, 0);
    acc[0][1] = __builtin_amdgcn_mfma_f32_16x16x32_bf16(a0, b1, acc[0][1], 0, 0, 0);
    acc[1][0] = __builtin_amdgcn_mfma_f32_16x16x32_bf16(a1, b0, acc[1][0], 0, 0, 0);
    acc[1][1] = __builtin_amdgcn_mfma_f32_16x16x32_bf16(a1, b1, acc[1][1], 0, 0, 0);
    __syncthreads();
  }

  short* Obf = (outsel == 0) ? Qh : Kh;
#pragma unroll
  for (int ni = 0; ni < 2; ++ni) {
    const int ocol = col0 + wn * 32 + ni * 16 + lc16;
    if (ocol >= N) continue;
    const float bb = bias[ocol];
#pragma unroll
    for (int mi = 0; mi < 2; ++mi)
#pragma unroll
      for (int r = 0; r < 4; ++r) {
        const int orow = row0 + wm * 32 + mi * 16 + g * 4 + r;
        const float val = acc[mi][ni][r] + bb;
        if (outsel == 2) {
          Vb[(size_t)orow * TDH + ocol] = val;
        } else {
          const int bI = orow >> 11, s = orow & 2047;
          const int hI = ocol >> 6, dh = ocol & 63;
          Obf[(((size_t)(bI * TH + hI) * TS + s) * TDH) + dh] = (short)f2bf(val);
        }
      }
  }
}

// ---------------------------------------------------------------------------
// Output projection GEMM (proven): x_out = Hd @ Wout(bf16) + bout.
// ---------------------------------------------------------------------------
__global__ __launch_bounds__(256) void gemm_out(
    const short* __restrict__ A, const short* __restrict__ W,
    const float* __restrict__ bias, float* __restrict__ Cf, int N, int Kd)
{
  __shared__ short As[64][40];
  __shared__ short Bs[64][40];

  const int tid  = threadIdx.x;
  const int w    = tid >> 6;
  const int lane = tid & 63;
  const int g    = lane >> 4;
  const int lc16 = lane & 15;
  const int wm   = w >> 1;
  const int wn   = w & 1;
  const int row0 = blockIdx.x * 64;
  const int col0 = blockIdx.y * 64;

  const int ar = tid >> 2;
  const int ak = (tid & 3) << 3;
  const int wk = tid >> 3;
  const int wn8 = (tid & 7) << 3;

  f32x4 acc[2][2];
#pragma unroll
  for (int i = 0; i < 2; ++i)
#pragma unroll
    for (int j = 0; j < 2; ++j) acc[i][j] = (f32x4){0.f, 0.f, 0.f, 0.f};

  for (int kt = 0; kt < Kd; kt += 32) {
    {
      short8v v = *(const short8v*)(A + (size_t)(row0 + ar) * Kd + kt + ak);
      *(short8v*)&As[ar][ak] = v;
    }
    {
      short8v v = *(const short8v*)(W + (size_t)(kt + wk) * N + col0 + wn8);
      Bs[wn8 + 0][wk] = v[0];
      Bs[wn8 + 1][wk] = v[1];
      Bs[wn8 + 2][wk] = v[2];
      Bs[wn8 + 3][wk] = v[3];
      Bs[wn8 + 4][wk] = v[4];
      Bs[wn8 + 5][wk] = v[5];
      Bs[wn8 + 6][wk] = v[6];
      Bs[wn8 + 7][wk] = v[7];
    }
    __syncthreads();

    short8v a0 = *(const short8v*)&As[wm * 32 + lc16][g * 8];
    short8v a1 = *(const short8v*)&As[wm * 32 + 16 + lc16][g * 8];
    short8v b0 = *(const short8v*)&Bs[wn * 32 + lc16][g * 8];
    short8v b1 = *(const short8v*)&Bs[wn * 32 + 16 + lc16][g * 8];
    acc[0][0] = __builtin_amdgcn_mfma_f32_16x16x32_bf16(a0, b0, acc[0][0], 0, 0, 0);
    acc[0][1] = __builtin_amdgcn_mfma_f32_16x16x32_bf16(a0, b1, acc[0][1], 0, 0, 0);
    acc[1][0] = __builtin_amdgcn_mfma_f32_16x16x32_bf16(a1, b0, acc[1][0], 0, 0, 0);
    acc[1][1] = __builtin_amdgcn_mfma_f32_16x16x32_bf16(a1, b1, acc[1][1], 0, 0, 0);
    __syncthreads();
  }

#pragma unroll
  for (int ni = 0; ni < 2; ++ni) {
    const int ocol = col0 + wn * 32 + ni * 16 + lc16;
    const float bb = bias[ocol];
#pragma unroll
    for (int mi = 0; mi < 2; ++mi)
#pragma unroll
      for (int r = 0; r < 4; ++r) {
        const int orow = row0 + wm * 32 + mi * 16 + g * 4 + r;
        Cf[(size_t)orow * N + ocol] = acc[mi][ni][r] + bb;
      }
  }
}

// ---------------------------------------------------------------------------
// zgemm (proven R14/R16): register NT-GEMM + LDS transpose, coalesced fp16
// Z writes. Block = 64q x 256j, one pair.
// ---------------------------------------------------------------------------
__global__ __launch_bounds__(256) void zgemm(
    const short* __restrict__ Qh, const short* __restrict__ Kh,
    _Float16* __restrict__ Zh, int q0s, int qc)
{
  __shared__ _Float16 Zt[64][264];

  const int tid  = threadIdx.x;
  const int w    = tid >> 6;
  const int lane = tid & 63;
  const int g    = lane >> 4;
  const int lc16 = lane & 15;
  const int pair = blockIdx.z;
  const int jb0  = blockIdx.x * 256;
  const int qlb  = blockIdx.y * 64;
  const int qb   = q0s + qlb;

  const short* Qp = Qh + (size_t)pair * TS * TDH;
  const short* Kp = Kh + (size_t)pair * TS * TDH;

  short8v bq[4][2];
#pragma unroll
  for (int ct = 0; ct < 4; ++ct) {
    const short* qp = Qp + (size_t)(qb + ct * 16 + lc16) * TDH + g * 8;
    bq[ct][0] = *(const short8v*)qp;
    bq[ct][1] = *(const short8v*)(qp + 32);
  }

  f32x4 acc[4][4];
#pragma unroll
  for (int rt = 0; rt < 4; ++rt)
#pragma unroll
    for (int ct = 0; ct < 4; ++ct) acc[rt][ct] = (f32x4){0.f, 0.f, 0.f, 0.f};

#pragma unroll
  for (int rt = 0; rt < 4; ++rt) {
    const short* kp = Kp + (size_t)(jb0 + w * 64 + rt * 16 + lc16) * TDH + g * 8;
    short8v ak0 = *(const short8v*)kp;
    short8v ak1 = *(const short8v*)(kp + 32);
#pragma unroll
    for (int ct = 0; ct < 4; ++ct) {
      acc[rt][ct] = __builtin_amdgcn_mfma_f32_16x16x32_bf16(ak0, bq[ct][0], acc[rt][ct], 0, 0, 0);
      acc[rt][ct] = __builtin_amdgcn_mfma_f32_16x16x32_bf16(ak1, bq[ct][1], acc[rt][ct], 0, 0, 0);
    }
  }

#pragma unroll
  for (int rt = 0; rt < 4; ++rt)
#pragma unroll
    for (int ct = 0; ct < 4; ++ct) {
      half4v o = {(_Float16)acc[rt][ct][0], (_Float16)acc[rt][ct][1],
                  (_Float16)acc[rt][ct][2], (_Float16)acc[rt][ct][3]};
      *(half4v*)&Zt[ct * 16 + lc16][w * 64 + rt * 16 + g * 4] = o;
    }
  __syncthreads();

  const int rseg = tid >> 5;
  const int jseg = (tid & 31) << 3;
#pragma unroll
  for (int i = 0; i < 8; ++i) {
    const int r = (i << 3) + rseg;
    half8v v = *(const half8v*)&Zt[r][jseg];
    *(half8v*)&Zh[((size_t)pair * qc + qlb + r) * TS + jb0 + jseg] = v;
  }
}

// ---------------------------------------------------------------------------
// spv (proven R14/R16): one block per (b,q), 512 thr = 8 waves, wave = head.
// ---------------------------------------------------------------------------
__global__ __launch_bounds__(512) void spv(
    const _Float16* __restrict__ Zh, const float* __restrict__ V,
    short* __restrict__ heads, float* __restrict__ avg,
    int q0s, int qc)
{
  __shared__ float avgS[TS];
  __shared__ unsigned short idxW[TH][CAP];
  __shared__ float pW[TH][CAP];
  __shared__ int cntW[TH];

  const int tid  = threadIdx.x;
  const int h    = tid >> 6;
  const int lane = tid & 63;
  const int ql   = blockIdx.x;
  const int bsel = blockIdx.y;
  const int q    = q0s + ql;
  const int row  = bsel * TS + q;
  const float* Vb = V + (size_t)bsel * TS * TDH;

  *(f32x4*)&avgS[tid << 2] = (f32x4){0.f, 0.f, 0.f, 0.f};
  if (lane == 0) cntW[h] = 0;
  __syncthreads();

  float za[4][8];
  const _Float16* zp = Zh + ((size_t)(bsel * TH + h) * qc + ql) * TS;
#pragma unroll
  for (int k = 0; k < 4; ++k) {
    half8v v = *(const half8v*)(zp + (k << 9) + (lane << 3));
#pragma unroll
    for (int c = 0; c < 8; ++c) za[k][c] = (float)v[c];
  }

  float m = za[0][0];
#pragma unroll
  for (int k = 0; k < 4; ++k)
#pragma unroll
    for (int c = 0; c < 8; ++c) m = fmaxf(m, za[k][c]);
#pragma unroll
  for (int s = 1; s < 64; s <<= 1) m = fmaxf(m, __shfl_xor(m, s));
  const float tau0 = m - 1.0f;

  float c0 = -1e30f, c1 = -1e30f, c2 = -1e30f, c3 = -1e30f;
  int j0 = 0, j1 = 0, j2 = 0, j3 = 0, nc = 0;
#pragma unroll
  for (int k = 0; k < 4; ++k)
#pragma unroll
    for (int c = 0; c < 8; ++c) {
      const float v = za[k][c];
      if (v > tau0) {
        c3 = c2; j3 = j2; c2 = c1; j2 = j1; c1 = c0; j1 = j0;
        c0 = v; j0 = (k << 9) + (lane << 3) + c; ++nc;
      }
    }
  const bool over = (__ballot(nc > 4) != 0ull);

  float tau = tau0;
  int prevc = -1;
  if (!over) {
    for (int it = 0; it < 64; ++it) {
      float s = 0.f, c = 0.f;
      if (c0 > tau) { s += c0; c += 1.f; }
      if (c1 > tau) { s += c1; c += 1.f; }
      if (c2 > tau) { s += c2; c += 1.f; }
      if (c3 > tau) { s += c3; c += 1.f; }
#pragma unroll
      for (int sh = 1; sh < 64; sh <<= 1) {
        s += __shfl_xor(s, sh);
        c += __shfl_xor(c, sh);
      }
      tau = (s - 1.f) / c;
      const int ci = (int)c;
      if (ci == prevc) break;
      prevc = ci;
    }
  } else {
    for (int it = 0; it < 64; ++it) {
      float s = 0.f, c = 0.f;
#pragma unroll
      for (int k = 0; k < 4; ++k)
#pragma unroll
        for (int cc = 0; cc < 8; ++cc) {
          const float v = za[k][cc];
          if (v > tau) { s += v; c += 1.f; }
        }
#pragma unroll
      for (int sh = 1; sh < 64; sh <<= 1) {
        s += __shfl_xor(s, sh);
        c += __shfl_xor(c, sh);
      }
      tau = (s - 1.f) / c;
      const int ci = (int)c;
      if (ci == prevc) break;
      prevc = ci;
    }
  }

  if (!over) {
    {
      const float p = c0 - tau;
      if (p > 0.f) {
        atomicAdd(&avgS[j0], p);
        const int pos = atomicAdd(&cntW[h], 1);
        if (pos < CAP) { idxW[h][pos] = (unsigned short)j0; pW[h][pos] = p; }
      }
    }
    {
      const float p = c1 - tau;
      if (p > 0.f) {
        atomicAdd(&avgS[j1], p);
        const int pos = atomicAdd(&cntW[h], 1);
        if (pos < CAP) { idxW[h][pos] = (unsigned short)j1; pW[h][pos] = p; }
      }
    }
    {
      const float p = c2 - tau;
      if (p > 0.f) {
        atomicAdd(&avgS[j2], p);
        const int pos = atomicAdd(&cntW[h], 1);
        if (pos < CAP) { idxW[h][pos] = (unsigned short)j2; pW[h][pos] = p; }
      }
    }
    {
      const float p = c3 - tau;
      if (p > 0.f) {
        atomicAdd(&avgS[j3], p);
        const int pos = atomicAdd(&cntW[h], 1);
        if (pos < CAP) { idxW[h][pos] = (unsigned short)j3; pW[h][pos] = p; }
      }
    }
  } else {
#pragma unroll
    for (int k = 0; k < 4; ++k)
#pragma unroll
      for (int cc = 0; cc < 8; ++cc) {
        const float p = za[k][cc] - tau;
        if (p > 0.f) {
          const int j = (k << 9) + (lane << 3) + cc;
          atomicAdd(&avgS[j], p);
          const int pos = atomicAdd(&cntW[h], 1);
          if (pos < CAP) { idxW[h][pos] = (unsigned short)j; pW[h][pos] = p; }
        }
      }
  }

  const int cnt = cntW[h];
  float a = 0.f;
  if (cnt <= CAP) {
    for (int e0 = 0; e0 < cnt; e0 += 8) {
      float pb[8], vb8[8];
#pragma unroll
      for (int u = 0; u < 8; ++u) {
        const int e = e0 + u;
        const int ec = (e < cnt) ? e : 0;
        pb[u] = (e < cnt) ? pW[h][ec] : 0.f;
        vb8[u] = Vb[(size_t)idxW[h][ec] * TDH + lane];
      }
#pragma unroll
      for (int u = 0; u < 8; ++u) a += pb[u] * vb8[u];
    }
  } else {
#pragma unroll
    for (int k = 0; k < 4; ++k)
#pragma unroll
      for (int cc = 0; cc < 8; ++cc) {
        const float p = za[k][cc] - tau;
        unsigned long long mask = __ballot(p > 0.f);
        while (mask) {
          const int src = __ffsll((long long)mask) - 1;
          mask &= mask - 1;
          const float pj = __shfl(p, src);
          const int j = (k << 9) + (src << 3) + cc;
          a += pj * Vb[(size_t)j * TDH + lane];
        }
      }
  }
  heads[(size_t)row * TD + h * TDH + lane] = (short)f2bf(a);

  __syncthreads();
  {
    f32x4 t = *(const f32x4*)&avgS[tid << 2];
    float4 o = {t[0] * 0.125f, t[1] * 0.125f, t[2] * 0.125f, t[3] * 0.125f};
    *(float4*)(avg + (size_t)row * TS + (tid << 2)) = o;
  }
}

// ---------------------------------------------------------------------------
extern "C" void kernel_launch(void* const* d_in, const int* in_sizes, int n_in,
                              void* d_out, int out_size, void* d_ws, size_t ws_size,
                              hipStream_t stream) {
  (void)in_sizes; (void)n_in; (void)out_size;

  const float* x    = (const float*)d_in[0];
  const float* Wq   = (const float*)d_in[1];
  const float* bq   = (const float*)d_in[2];
  const float* Wk   = (const float*)d_in[3];
  const float* bk   = (const float*)d_in[4];
  const float* Wv   = (const float*)d_in[5];
  const float* bv   = (const float*)d_in[6];
  const float* Wout = (const float*)d_in[7];
  const float* bout = (const float*)d_in[8];

  float* out   = (float*)d_out;
  float* x_out = out;                       // [2,2048,512]
  float* avg   = out + 2097152;             // [2,2048,2048]

  float* ws = (float*)d_ws;
  float* Vb = ws;                           // f32 [2][2048][64]
  short* Hd = (short*)(ws + 262144);        // bf16 [4096][512]
  short* Qh = (short*)(ws + 1310720);       // bf16 [16][2048][64]
  short* Kh = (short*)(ws + 2359296);       // bf16 [16][2048][64]
  short* Wqb = (short*)(ws + 3407872);      // bf16 [512][512]
  short* Wkb = (short*)(ws + 3538944);      // bf16 [512][512]
  short* Wvb = (short*)(ws + 3670016);      // bf16 [512][64]
  short* Wob = (short*)(ws + 3686400);      // bf16 [512][512]
  _Float16* Zh = (_Float16*)(ws + 3817472); // fp16 slab [16][qc][2048]
  short* xbuf = (short*)(ws + 3817472);     // bf16 [4096][512] (aliases Zh head)

  // q-chunk: capped at QCMAX so the slab (16*qc*2048*2B) stays L3-resident
  const size_t wsFloats = ws_size / 4;
  const size_t base = 3817472;
  int qc = 64;
  for (int cand = QCMAX; cand >= 64; cand >>= 1) {
    if (base + (size_t)16 * cand * 1024 <= wsFloats) { qc = cand; break; }
  }

  const dim3 blk(256);
  const int BS = 2 * TS;                    // 4096 rows

  cvt_all<<<dim3(1424), blk, 0, stream>>>(x, Wq, Wk, Wv, Wout, xbuf, Wqb, Wkb, Wvb, Wob);
  proj_gemm<<<dim3(BS / 64, 17), blk, 0, stream>>>(xbuf, Wqb, bq, Wkb, bk, Wvb, bv, Qh, Kh, Vb);

  for (int q0s = 0; q0s < TS; q0s += qc) {
    zgemm<<<dim3(TS / 256, qc / 64, 16), blk, 0, stream>>>(Qh, Kh, Zh, q0s, qc);
    spv<<<dim3(qc, 2), dim3(512), 0, stream>>>(Zh, Vb, Hd, avg, q0s, qc);
  }

  gemm_out<<<dim3(BS / 64, TD / 64), blk, 0, stream>>>(Hd, Wob, bout, x_out, TD, TD);
}

// Round 18
// 139.236 us; speedup vs baseline: 1.1114x; 1.1114x over previous
//
#include <hip/hip_runtime.h>
#include <cstddef>
#include <cstdint>

#define TS 2048   // sequence length S
#define TD 512    // model dim D
#define TH 8      // heads
#define TDH 64    // head dim
#define CAP 256   // support entries per head list (ballot fallback beyond)

typedef float f32x4 __attribute__((ext_vector_type(4)));
typedef short short8v __attribute__((ext_vector_type(8)));
typedef _Float16 half4v __attribute__((ext_vector_type(4)));
typedef _Float16 half8v __attribute__((ext_vector_type(8)));

__device__ __forceinline__ unsigned short f2bf(float f) {
  unsigned u = __builtin_bit_cast(unsigned, f);
  u += 0x7fff + ((u >> 16) & 1);          // RNE
  return (unsigned short)(u >> 16);
}

// ---------------------------------------------------------------------------
// cvt_all: one launch converts x, Wq, Wk, Wv, Wout -> bf16 buffers.
// ---------------------------------------------------------------------------
__global__ __launch_bounds__(256) void cvt_all(
    const float* __restrict__ x,  const float* __restrict__ Wq,
    const float* __restrict__ Wk, const float* __restrict__ Wv,
    const float* __restrict__ Wout,
    short* __restrict__ xb,  short* __restrict__ Wqb,
    short* __restrict__ Wkb, short* __restrict__ Wvb,
    short* __restrict__ Wob)
{
  const int b = blockIdx.x;
  const float* src; short* dst; int off;
  if (b < 1024)      { src = x;    dst = xb;  off = b; }
  else if (b < 1152) { src = Wq;   dst = Wqb; off = b - 1024; }
  else if (b < 1280) { src = Wk;   dst = Wkb; off = b - 1152; }
  else if (b < 1296) { src = Wv;   dst = Wvb; off = b - 1280; }
  else               { src = Wout; dst = Wob; off = b - 1296; }
  const int i = (off * 256 + threadIdx.x) << 3;
  float4 f0 = *(const float4*)(src + i);
  float4 f1 = *(const float4*)(src + i + 4);
  short8v v;
  v[0] = (short)f2bf(f0.x); v[1] = (short)f2bf(f0.y);
  v[2] = (short)f2bf(f0.z); v[3] = (short)f2bf(f0.w);
  v[4] = (short)f2bf(f1.x); v[5] = (short)f2bf(f1.y);
  v[6] = (short)f2bf(f1.z); v[7] = (short)f2bf(f1.w);
  *(short8v*)(dst + i) = v;
}

// ---------------------------------------------------------------------------
// Fused QKV projection (proven R9-R16).
// ---------------------------------------------------------------------------
__global__ __launch_bounds__(256) void proj_gemm(
    const short* __restrict__ xb,
    const short* __restrict__ Wqb, const float* __restrict__ bq,
    const short* __restrict__ Wkb, const float* __restrict__ bk,
    const short* __restrict__ Wvb, const float* __restrict__ bv,
    short* __restrict__ Qh, short* __restrict__ Kh, float* __restrict__ Vb)
{
  __shared__ short As[64][40];
  __shared__ short Bs[64][40];

  const int by = blockIdx.y;
  const short* W; const float* bias; int N; int col0; int outsel;
  if (by < 8)       { W = Wqb; bias = bq; N = TD;  col0 = by * 64;       outsel = 0; }
  else if (by < 16) { W = Wkb; bias = bk; N = TD;  col0 = (by - 8) * 64; outsel = 1; }
  else              { W = Wvb; bias = bv; N = TDH; col0 = 0;             outsel = 2; }

  const int tid  = threadIdx.x;
  const int w    = tid >> 6;
  const int lane = tid & 63;
  const int g    = lane >> 4;
  const int lc16 = lane & 15;
  const int wm   = w >> 1;
  const int wn   = w & 1;
  const int row0 = blockIdx.x * 64;

  const int ar = tid >> 2;
  const int ak = (tid & 3) << 3;
  const int wk = tid >> 3;
  const int wn8 = (tid & 7) << 3;

  f32x4 acc[2][2];
#pragma unroll
  for (int i = 0; i < 2; ++i)
#pragma unroll
    for (int j = 0; j < 2; ++j) acc[i][j] = (f32x4){0.f, 0.f, 0.f, 0.f};

  for (int kt = 0; kt < TD; kt += 32) {
    {
      short8v v = *(const short8v*)(xb + (size_t)(row0 + ar) * TD + kt + ak);
      *(short8v*)&As[ar][ak] = v;
    }
    {
      short8v v = *(const short8v*)(W + (size_t)(kt + wk) * N + col0 + wn8);
      Bs[wn8 + 0][wk] = v[0];
      Bs[wn8 + 1][wk] = v[1];
      Bs[wn8 + 2][wk] = v[2];
      Bs[wn8 + 3][wk] = v[3];
      Bs[wn8 + 4][wk] = v[4];
      Bs[wn8 + 5][wk] = v[5];
      Bs[wn8 + 6][wk] = v[6];
      Bs[wn8 + 7][wk] = v[7];
    }
    __syncthreads();

    short8v a0 = *(const short8v*)&As[wm * 32 + lc16][g * 8];
    short8v a1 = *(const short8v*)&As[wm * 32 + 16 + lc16][g * 8];
    short8v b0 = *(const short8v*)&Bs[wn * 32 + lc16][g * 8];
    short8v b1 = *(const short8v*)&Bs[wn * 32 + 16 + lc16][g * 8];
    acc[0][0] = __builtin_amdgcn_mfma_f32_16x16x32_bf16(a0, b0, acc[0][0], 0, 0, 0);
    acc[0][1] = __builtin_amdgcn_mfma_f32_16x16x32_bf16(a0, b1, acc[0][1], 0, 0, 0);
    acc[1][0] = __builtin_amdgcn_mfma_f32_16x16x32_bf16(a1, b0, acc[1][0], 0, 0, 0);
    acc[1][1] = __builtin_amdgcn_mfma_f32_16x16x32_bf16(a1, b1, acc[1][1], 0, 0, 0);
    __syncthreads();
  }

  short* Obf = (outsel == 0) ? Qh : Kh;
#pragma unroll
  for (int ni = 0; ni < 2; ++ni) {
    const int ocol = col0 + wn * 32 + ni * 16 + lc16;
    if (ocol >= N) continue;
    const float bb = bias[ocol];
#pragma unroll
    for (int mi = 0; mi < 2; ++mi)
#pragma unroll
      for (int r = 0; r < 4; ++r) {
        const int orow = row0 + wm * 32 + mi * 16 + g * 4 + r;
        const float val = acc[mi][ni][r] + bb;
        if (outsel == 2) {
          Vb[(size_t)orow * TDH + ocol] = val;
        } else {
          const int bI = orow >> 11, s = orow & 2047;
          const int hI = ocol >> 6, dh = ocol & 63;
          Obf[(((size_t)(bI * TH + hI) * TS + s) * TDH) + dh] = (short)f2bf(val);
        }
      }
  }
}

// ---------------------------------------------------------------------------
// Output projection GEMM (proven): x_out = Hd @ Wout(bf16) + bout.
// ---------------------------------------------------------------------------
__global__ __launch_bounds__(256) void gemm_out(
    const short* __restrict__ A, const short* __restrict__ W,
    const float* __restrict__ bias, float* __restrict__ Cf, int N, int Kd)
{
  __shared__ short As[64][40];
  __shared__ short Bs[64][40];

  const int tid  = threadIdx.x;
  const int w    = tid >> 6;
  const int lane = tid & 63;
  const int g    = lane >> 4;
  const int lc16 = lane & 15;
  const int wm   = w >> 1;
  const int wn   = w & 1;
  const int row0 = blockIdx.x * 64;
  const int col0 = blockIdx.y * 64;

  const int ar = tid >> 2;
  const int ak = (tid & 3) << 3;
  const int wk = tid >> 3;
  const int wn8 = (tid & 7) << 3;

  f32x4 acc[2][2];
#pragma unroll
  for (int i = 0; i < 2; ++i)
#pragma unroll
    for (int j = 0; j < 2; ++j) acc[i][j] = (f32x4){0.f, 0.f, 0.f, 0.f};

  for (int kt = 0; kt < Kd; kt += 32) {
    {
      short8v v = *(const short8v*)(A + (size_t)(row0 + ar) * Kd + kt + ak);
      *(short8v*)&As[ar][ak] = v;
    }
    {
      short8v v = *(const short8v*)(W + (size_t)(kt + wk) * N + col0 + wn8);
      Bs[wn8 + 0][wk] = v[0];
      Bs[wn8 + 1][wk] = v[1];
      Bs[wn8 + 2][wk] = v[2];
      Bs[wn8 + 3][wk] = v[3];
      Bs[wn8 + 4][wk] = v[4];
      Bs[wn8 + 5][wk] = v[5];
      Bs[wn8 + 6][wk] = v[6];
      Bs[wn8 + 7][wk] = v[7];
    }
    __syncthreads();

    short8v a0 = *(const short8v*)&As[wm * 32 + lc16][g * 8];
    short8v a1 = *(const short8v*)&As[wm * 32 + 16 + lc16][g * 8];
    short8v b0 = *(const short8v*)&Bs[wn * 32 + lc16][g * 8];
    short8v b1 = *(const short8v*)&Bs[wn * 32 + 16 + lc16][g * 8];
    acc[0][0] = __builtin_amdgcn_mfma_f32_16x16x32_bf16(a0, b0, acc[0][0], 0, 0, 0);
    acc[0][1] = __builtin_amdgcn_mfma_f32_16x16x32_bf16(a0, b1, acc[0][1], 0, 0, 0);
    acc[1][0] = __builtin_amdgcn_mfma_f32_16x16x32_bf16(a1, b0, acc[1][0], 0, 0, 0);
    acc[1][1] = __builtin_amdgcn_mfma_f32_16x16x32_bf16(a1, b1, acc[1][1], 0, 0, 0);
    __syncthreads();
  }

#pragma unroll
  for (int ni = 0; ni < 2; ++ni) {
    const int ocol = col0 + wn * 32 + ni * 16 + lc16;
    const float bb = bias[ocol];
#pragma unroll
    for (int mi = 0; mi < 2; ++mi)
#pragma unroll
      for (int r = 0; r < 4; ++r) {
        const int orow = row0 + wm * 32 + mi * 16 + g * 4 + r;
        Cf[(size_t)orow * N + ocol] = acc[mi][ni][r] + bb;
      }
  }
}

// ---------------------------------------------------------------------------
// zgemm (proven R14/R16): register NT-GEMM + LDS transpose, coalesced fp16
// Z writes. Block = 64q x 256j, one pair.
// ---------------------------------------------------------------------------
__global__ __launch_bounds__(256) void zgemm(
    const short* __restrict__ Qh, const short* __restrict__ Kh,
    _Float16* __restrict__ Zh, int q0s, int qc)
{
  __shared__ _Float16 Zt[64][264];

  const int tid  = threadIdx.x;
  const int w    = tid >> 6;
  const int lane = tid & 63;
  const int g    = lane >> 4;
  const int lc16 = lane & 15;
  const int pair = blockIdx.z;
  const int jb0  = blockIdx.x * 256;
  const int qlb  = blockIdx.y * 64;
  const int qb   = q0s + qlb;

  const short* Qp = Qh + (size_t)pair * TS * TDH;
  const short* Kp = Kh + (size_t)pair * TS * TDH;

  short8v bq[4][2];
#pragma unroll
  for (int ct = 0; ct < 4; ++ct) {
    const short* qp = Qp + (size_t)(qb + ct * 16 + lc16) * TDH + g * 8;
    bq[ct][0] = *(const short8v*)qp;
    bq[ct][1] = *(const short8v*)(qp + 32);
  }

  f32x4 acc[4][4];
#pragma unroll
  for (int rt = 0; rt < 4; ++rt)
#pragma unroll
    for (int ct = 0; ct < 4; ++ct) acc[rt][ct] = (f32x4){0.f, 0.f, 0.f, 0.f};

#pragma unroll
  for (int rt = 0; rt < 4; ++rt) {
    const short* kp = Kp + (size_t)(jb0 + w * 64 + rt * 16 + lc16) * TDH + g * 8;
    short8v ak0 = *(const short8v*)kp;
    short8v ak1 = *(const short8v*)(kp + 32);
#pragma unroll
    for (int ct = 0; ct < 4; ++ct) {
      acc[rt][ct] = __builtin_amdgcn_mfma_f32_16x16x32_bf16(ak0, bq[ct][0], acc[rt][ct], 0, 0, 0);
      acc[rt][ct] = __builtin_amdgcn_mfma_f32_16x16x32_bf16(ak1, bq[ct][1], acc[rt][ct], 0, 0, 0);
    }
  }

#pragma unroll
  for (int rt = 0; rt < 4; ++rt)
#pragma unroll
    for (int ct = 0; ct < 4; ++ct) {
      half4v o = {(_Float16)acc[rt][ct][0], (_Float16)acc[rt][ct][1],
                  (_Float16)acc[rt][ct][2], (_Float16)acc[rt][ct][3]};
      *(half4v*)&Zt[ct * 16 + lc16][w * 64 + rt * 16 + g * 4] = o;
    }
  __syncthreads();

  const int rseg = tid >> 5;
  const int jseg = (tid & 31) << 3;
#pragma unroll
  for (int i = 0; i < 8; ++i) {
    const int r = (i << 3) + rseg;
    half8v v = *(const half8v*)&Zt[r][jseg];
    *(half8v*)&Zh[((size_t)pair * qc + qlb + r) * TS + jb0 + jseg] = v;
  }
}

// ---------------------------------------------------------------------------
// spv (proven R14/R16): one block per (b,q), 512 thr = 8 waves, wave = head.
// ---------------------------------------------------------------------------
__global__ __launch_bounds__(512) void spv(
    const _Float16* __restrict__ Zh, const float* __restrict__ V,
    short* __restrict__ heads, float* __restrict__ avg,
    int q0s, int qc)
{
  __shared__ float avgS[TS];
  __shared__ unsigned short idxW[TH][CAP];
  __shared__ float pW[TH][CAP];
  __shared__ int cntW[TH];

  const int tid  = threadIdx.x;
  const int h    = tid >> 6;
  const int lane = tid & 63;
  const int ql   = blockIdx.x;
  const int bsel = blockIdx.y;
  const int q    = q0s + ql;
  const int row  = bsel * TS + q;
  const float* Vb = V + (size_t)bsel * TS * TDH;

  *(f32x4*)&avgS[tid << 2] = (f32x4){0.f, 0.f, 0.f, 0.f};
  if (lane == 0) cntW[h] = 0;
  __syncthreads();

  float za[4][8];
  const _Float16* zp = Zh + ((size_t)(bsel * TH + h) * qc + ql) * TS;
#pragma unroll
  for (int k = 0; k < 4; ++k) {
    half8v v = *(const half8v*)(zp + (k << 9) + (lane << 3));
#pragma unroll
    for (int c = 0; c < 8; ++c) za[k][c] = (float)v[c];
  }

  float m = za[0][0];
#pragma unroll
  for (int k = 0; k < 4; ++k)
#pragma unroll
    for (int c = 0; c < 8; ++c) m = fmaxf(m, za[k][c]);
#pragma unroll
  for (int s = 1; s < 64; s <<= 1) m = fmaxf(m, __shfl_xor(m, s));
  const float tau0 = m - 1.0f;

  float c0 = -1e30f, c1 = -1e30f, c2 = -1e30f, c3 = -1e30f;
  int j0 = 0, j1 = 0, j2 = 0, j3 = 0, nc = 0;
#pragma unroll
  for (int k = 0; k < 4; ++k)
#pragma unroll
    for (int c = 0; c < 8; ++c) {
      const float v = za[k][c];
      if (v > tau0) {
        c3 = c2; j3 = j2; c2 = c1; j2 = j1; c1 = c0; j1 = j0;
        c0 = v; j0 = (k << 9) + (lane << 3) + c; ++nc;
      }
    }
  const bool over = (__ballot(nc > 4) != 0ull);

  float tau = tau0;
  int prevc = -1;
  if (!over) {
    for (int it = 0; it < 64; ++it) {
      float s = 0.f, c = 0.f;
      if (c0 > tau) { s += c0; c += 1.f; }
      if (c1 > tau) { s += c1; c += 1.f; }
      if (c2 > tau) { s += c2; c += 1.f; }
      if (c3 > tau) { s += c3; c += 1.f; }
#pragma unroll
      for (int sh = 1; sh < 64; sh <<= 1) {
        s += __shfl_xor(s, sh);
        c += __shfl_xor(c, sh);
      }
      tau = (s - 1.f) / c;
      const int ci = (int)c;
      if (ci == prevc) break;
      prevc = ci;
    }
  } else {
    for (int it = 0; it < 64; ++it) {
      float s = 0.f, c = 0.f;
#pragma unroll
      for (int k = 0; k < 4; ++k)
#pragma unroll
        for (int cc = 0; cc < 8; ++cc) {
          const float v = za[k][cc];
          if (v > tau) { s += v; c += 1.f; }
        }
#pragma unroll
      for (int sh = 1; sh < 64; sh <<= 1) {
        s += __shfl_xor(s, sh);
        c += __shfl_xor(c, sh);
      }
      tau = (s - 1.f) / c;
      const int ci = (int)c;
      if (ci == prevc) break;
      prevc = ci;
    }
  }

  if (!over) {
    {
      const float p = c0 - tau;
      if (p > 0.f) {
        atomicAdd(&avgS[j0], p);
        const int pos = atomicAdd(&cntW[h], 1);
        if (pos < CAP) { idxW[h][pos] = (unsigned short)j0; pW[h][pos] = p; }
      }
    }
    {
      const float p = c1 - tau;
      if (p > 0.f) {
        atomicAdd(&avgS[j1], p);
        const int pos = atomicAdd(&cntW[h], 1);
        if (pos < CAP) { idxW[h][pos] = (unsigned short)j1; pW[h][pos] = p; }
      }
    }
    {
      const float p = c2 - tau;
      if (p > 0.f) {
        atomicAdd(&avgS[j2], p);
        const int pos = atomicAdd(&cntW[h], 1);
        if (pos < CAP) { idxW[h][pos] = (unsigned short)j2; pW[h][pos] = p; }
      }
    }
    {
      const float p = c3 - tau;
      if (p > 0.f) {
        atomicAdd(&avgS[j3], p);
        const int pos = atomicAdd(&cntW[h], 1);
        if (pos < CAP) { idxW[h][pos] = (unsigned short)j3; pW[h][pos] = p; }
      }
    }
  } else {
#pragma unroll
    for (int k = 0; k < 4; ++k)
#pragma unroll
      for (int cc = 0; cc < 8; ++cc) {
        const float p = za[k][cc] - tau;
        if (p > 0.f) {
          const int j = (k << 9) + (lane << 3) + cc;
          atomicAdd(&avgS[j], p);
          const int pos = atomicAdd(&cntW[h], 1);
          if (pos < CAP) { idxW[h][pos] = (unsigned short)j; pW[h][pos] = p; }
        }
      }
  }

  const int cnt = cntW[h];
  float a = 0.f;
  if (cnt <= CAP) {
    for (int e0 = 0; e0 < cnt; e0 += 8) {
      float pb[8], vb8[8];
#pragma unroll
      for (int u = 0; u < 8; ++u) {
        const int e = e0 + u;
        const int ec = (e < cnt) ? e : 0;
        pb[u] = (e < cnt) ? pW[h][ec] : 0.f;
        vb8[u] = Vb[(size_t)idxW[h][ec] * TDH + lane];
      }
#pragma unroll
      for (int u = 0; u < 8; ++u) a += pb[u] * vb8[u];
    }
  } else {
#pragma unroll
    for (int k = 0; k < 4; ++k)
#pragma unroll
      for (int cc = 0; cc < 8; ++cc) {
        const float p = za[k][cc] - tau;
        unsigned long long mask = __ballot(p > 0.f);
        while (mask) {
          const int src = __ffsll((long long)mask) - 1;
          mask &= mask - 1;
          const float pj = __shfl(p, src);
          const int j = (k << 9) + (src << 3) + cc;
          a += pj * Vb[(size_t)j * TDH + lane];
        }
      }
  }
  heads[(size_t)row * TD + h * TDH + lane] = (short)f2bf(a);

  __syncthreads();
  {
    f32x4 t = *(const f32x4*)&avgS[tid << 2];
    float4 o = {t[0] * 0.125f, t[1] * 0.125f, t[2] * 0.125f, t[3] * 0.125f};
    *(float4*)(avg + (size_t)row * TS + (tid << 2)) = o;
  }
}

// ---------------------------------------------------------------------------
extern "C" void kernel_launch(void* const* d_in, const int* in_sizes, int n_in,
                              void* d_out, int out_size, void* d_ws, size_t ws_size,
                              hipStream_t stream) {
  (void)in_sizes; (void)n_in; (void)out_size;

  const float* x    = (const float*)d_in[0];
  const float* Wq   = (const float*)d_in[1];
  const float* bq   = (const float*)d_in[2];
  const float* Wk   = (const float*)d_in[3];
  const float* bk   = (const float*)d_in[4];
  const float* Wv   = (const float*)d_in[5];
  const float* bv   = (const float*)d_in[6];
  const float* Wout = (const float*)d_in[7];
  const float* bout = (const float*)d_in[8];

  float* out   = (float*)d_out;
  float* x_out = out;                       // [2,2048,512]
  float* avg   = out + 2097152;             // [2,2048,2048]

  float* ws = (float*)d_ws;
  float* Vb = ws;                           // f32 [2][2048][64]
  short* Hd = (short*)(ws + 262144);        // bf16 [4096][512]
  short* Qh = (short*)(ws + 1310720);       // bf16 [16][2048][64]
  short* Kh = (short*)(ws + 2359296);       // bf16 [16][2048][64]
  short* Wqb = (short*)(ws + 3407872);      // bf16 [512][512]
  short* Wkb = (short*)(ws + 3538944);      // bf16 [512][512]
  short* Wvb = (short*)(ws + 3670016);      // bf16 [512][64]
  short* Wob = (short*)(ws + 3686400);      // bf16 [512][512]
  _Float16* Zh = (_Float16*)(ws + 3817472); // fp16 slab [16][qc][2048]
  short* xbuf = (short*)(ws + 3817472);     // bf16 [4096][512] (aliases Zh head)

  // largest q-chunk (all 16 pairs resident) fitting the workspace
  const size_t wsFloats = ws_size / 4;
  const size_t base = 3817472;
  int qc = 64;
  for (int cand = 2048; cand >= 64; cand >>= 1) {
    if (base + (size_t)16 * cand * 1024 <= wsFloats) { qc = cand; break; }
  }

  const dim3 blk(256);
  const int BS = 2 * TS;                    // 4096 rows

  cvt_all<<<dim3(1424), blk, 0, stream>>>(x, Wq, Wk, Wv, Wout, xbuf, Wqb, Wkb, Wvb, Wob);
  proj_gemm<<<dim3(BS / 64, 17), blk, 0, stream>>>(xbuf, Wqb, bq, Wkb, bk, Wvb, bv, Qh, Kh, Vb);

  for (int q0s = 0; q0s < TS; q0s += qc) {
    zgemm<<<dim3(TS / 256, qc / 64, 16), blk, 0, stream>>>(Qh, Kh, Zh, q0s, qc);
    spv<<<dim3(qc, 2), dim3(512), 0, stream>>>(Zh, Vb, Hd, avg, q0s, qc);
  }

  gemm_out<<<dim3(BS / 64, TD / 64), blk, 0, stream>>>(Hd, Wob, bout, x_out, TD, TD);
}